// Round 3
// baseline (504.256 us; speedup 1.0000x reference)
//
#include <hip/hip_runtime.h>
#include <hip/hip_bf16.h>
#include <cstddef>
#include <cstdint>

// ---------------- problem constants ----------------
#define M_TOK   16384      // 32*512 tokens
#define N_CODE  8192       // NUM_LATENTS
#define K_DIM   256        // LATENT_DIM
#define NSPLIT  8          // R3: 4->8. 1024 blocks = 4 blocks/CU (LDS 34.8KB*4 < 160KB,
                           // VGPR 104 <= 128) to hide the vmcnt(0)-before-barrier drain
#define BM      128
#define BN      128
#define BK      32

typedef short bf16x8 __attribute__((ext_vector_type(8)));  // 8 bf16 = 4 VGPRs
typedef float f32x4  __attribute__((ext_vector_type(4)));

__device__ __forceinline__ unsigned short f2bf_rne(float f) {
    unsigned u = __float_as_uint(f);
    unsigned r = u + 0x7FFFu + ((u >> 16) & 1u);
    return (unsigned short)(r >> 16);
}
__device__ __forceinline__ float bf2f(unsigned short h) {
    union { unsigned u; float f; } c; c.u = ((unsigned)h) << 16; return c.f;
}

__device__ __forceinline__ void gload16(const void* g, void* l) {
    __builtin_amdgcn_global_load_lds(
        (const __attribute__((address_space(1))) void*)g,
        (__attribute__((address_space(3))) void*)l, 16, 0, 0);
}

// ---------------- prep: bf16 hi/lo split + fp32 norms ----------------
// one wave per row; lane l handles float4 l (256 floats = 64 lanes * 4)
__global__ void vq_prep(const float* __restrict__ x, const float* __restrict__ cb,
                        unsigned short* __restrict__ xh, unsigned short* __restrict__ xl,
                        unsigned short* __restrict__ wh, unsigned short* __restrict__ wl,
                        float* __restrict__ x2, float* __restrict__ w2) {
    int gt   = blockIdx.x * blockDim.x + threadIdx.x;
    int row  = gt >> 6;
    int lane = gt & 63;
    if (row >= M_TOK + N_CODE) return;
    const float* src; unsigned short *dh, *dl; float* dn;
    if (row < M_TOK) {
        src = x + (size_t)row * K_DIM;
        dh = xh + (size_t)row * K_DIM; dl = xl + (size_t)row * K_DIM; dn = x2 + row;
    } else {
        int r = row - M_TOK;
        src = cb + (size_t)r * K_DIM;
        dh = wh + (size_t)r * K_DIM; dl = wl + (size_t)r * K_DIM; dn = w2 + r;
    }
    float4 v = ((const float4*)src)[lane];
    unsigned short h0 = f2bf_rne(v.x), h1 = f2bf_rne(v.y);
    unsigned short h2 = f2bf_rne(v.z), h3 = f2bf_rne(v.w);
    unsigned short l0 = f2bf_rne(v.x - bf2f(h0)), l1 = f2bf_rne(v.y - bf2f(h1));
    unsigned short l2 = f2bf_rne(v.z - bf2f(h2)), l3 = f2bf_rne(v.w - bf2f(h3));
    ushort4 hv; hv.x = h0; hv.y = h1; hv.z = h2; hv.w = h3;
    ushort4 lv; lv.x = l0; lv.y = l1; lv.z = l2; lv.w = l3;
    ((ushort4*)dh)[lane] = hv;
    ((ushort4*)dl)[lane] = lv;
    float s = v.x*v.x + v.y*v.y + v.z*v.z + v.w*v.w;
    #pragma unroll
    for (int off = 32; off > 0; off >>= 1) s += __shfl_down(s, off);
    if (lane == 0) *dn = s;
}

// ---------------- main: 3-term bf16 MFMA GEMM fused with argmin ----------------
__global__ __launch_bounds__(256, 4)
void vq_main_mfma(const unsigned short* __restrict__ xh, const unsigned short* __restrict__ xl,
                  const unsigned short* __restrict__ wh, const unsigned short* __restrict__ wl,
                  const float* __restrict__ x2, const float* __restrict__ w2,
                  float* __restrict__ pminv, int* __restrict__ pmini) {
    // LDS tiles: [128 rows][32 bf16] row-major, 64 B per row (8 KB each)
    __shared__ unsigned short xh_s[BM][BK];
    __shared__ unsigned short xl_s[BM][BK];
    __shared__ unsigned short wh_s[BN][BK];
    __shared__ unsigned short wl_s[BN][BK];
    __shared__ float red_d[BM][2];
    __shared__ int   red_i[BM][2];

    const int split = blockIdx.x;            // 0..NSPLIT-1
    const int mtile = blockIdx.y;            // 0..127
    const int gm    = mtile * BM;
    const int tid   = threadIdx.x;
    const int w     = tid >> 6;              // wave 0..3
    const int lane  = tid & 63;
    const int wr    = w >> 1;                // row half (0/1)
    const int wc    = w & 1;                 // col half (0/1)
    const int quad  = lane >> 4;             // 0..3
    const int l15   = lane & 15;

    // staging addressing (wave w stages rows [w*32, w*32+32) of each array)
    const int w32   = w * 32;
    const int srow  = (lane >> 2);           // 0..15 within 16-row chunk
    const int sc16  = (lane & 3) * 16;       // byte offset within 64B row chunk

    // per-lane row constants
    float x2r[16];
    #pragma unroll
    for (int rt = 0; rt < 4; ++rt)
        #pragma unroll
        for (int reg = 0; reg < 4; ++reg)
            x2r[rt*4+reg] = x2[gm + wr*64 + rt*16 + quad*4 + reg];

    float minv[16];
    int   mini[16];
    #pragma unroll
    for (int i = 0; i < 16; ++i) { minv[i] = 3.4e38f; mini[i] = 0; }

    const char* xhp = (const char*)xh;
    const char* xlp = (const char*)xl;
    const char* whp = (const char*)wh;
    const char* wlp = (const char*)wl;

    const int tiles = (N_CODE / NSPLIT) / BN;    // 8
    for (int tile = 0; tile < tiles; ++tile) {
        const int nb = split * (N_CODE / NSPLIT) + tile * BN;

        f32x4 acc[4][4];
        #pragma unroll
        for (int rt = 0; rt < 4; ++rt)
            #pragma unroll
            for (int ct = 0; ct < 4; ++ct)
                acc[rt][ct] = (f32x4){0.f, 0.f, 0.f, 0.f};

        for (int kc = 0; kc < K_DIM / BK; ++kc) {
            __syncthreads();     // protect LDS from previous iteration's readers
            #pragma unroll
            for (int i = 0; i < 2; ++i) {
                int r = w32 + i * 16 + srow;            // tile row this lane fetches
                size_t xoff = (size_t)(gm + r) * (K_DIM*2) + kc*(BK*2) + sc16;
                size_t woff = (size_t)(nb + r) * (K_DIM*2) + kc*(BK*2) + sc16;
                unsigned ldso = (unsigned)(w32 + i * 16) * (BK*2);
                gload16(xhp + xoff, (char*)&xh_s[0][0] + ldso);
                gload16(xlp + xoff, (char*)&xl_s[0][0] + ldso);
                gload16(whp + woff, (char*)&wh_s[0][0] + ldso);
                gload16(wlp + woff, (char*)&wl_s[0][0] + ldso);
            }
            __syncthreads();     // staging complete

            bf16x8 ah[4], al[4], bh[4], bl[4];
            const int ko = quad * 16;    // byte offset along K: (lane>>4)*8 bf16
            #pragma unroll
            for (int rt = 0; rt < 4; ++rt) {
                int off = (wr*64 + rt*16 + l15) * (BK*2) + ko;
                ah[rt] = *(const bf16x8*)((const char*)&xh_s[0][0] + off);
                al[rt] = *(const bf16x8*)((const char*)&xl_s[0][0] + off);
            }
            #pragma unroll
            for (int ct = 0; ct < 4; ++ct) {
                int off = (wc*64 + ct*16 + l15) * (BK*2) + ko;
                bh[ct] = *(const bf16x8*)((const char*)&wh_s[0][0] + off);
                bl[ct] = *(const bf16x8*)((const char*)&wl_s[0][0] + off);
            }
            #pragma unroll
            for (int rt = 0; rt < 4; ++rt)
                #pragma unroll
                for (int ct = 0; ct < 4; ++ct) {
                    acc[rt][ct] = __builtin_amdgcn_mfma_f32_16x16x32_bf16(al[rt], bh[ct], acc[rt][ct], 0, 0, 0);
                    acc[rt][ct] = __builtin_amdgcn_mfma_f32_16x16x32_bf16(ah[rt], bl[ct], acc[rt][ct], 0, 0, 0);
                    acc[rt][ct] = __builtin_amdgcn_mfma_f32_16x16x32_bf16(ah[rt], bh[ct], acc[rt][ct], 0, 0, 0);
                }
        }

        // score tile: dist = (x2 - 2*xw) + w2, C layout col=lane&15, row=quad*4+reg
        float w2c[4];
        int   cidx[4];
        #pragma unroll
        for (int ct = 0; ct < 4; ++ct) {
            cidx[ct] = nb + wc*64 + ct*16 + l15;
            w2c[ct]  = w2[cidx[ct]];
        }
        #pragma unroll
        for (int rt = 0; rt < 4; ++rt)
            #pragma unroll
            for (int ct = 0; ct < 4; ++ct) {
                #pragma unroll
                for (int reg = 0; reg < 4; ++reg) {
                    float d = (x2r[rt*4+reg] - 2.0f * acc[rt][ct][reg]) + w2c[ct];
                    int r16 = rt*4 + reg;
                    if (d < minv[r16]) { minv[r16] = d; mini[r16] = cidx[ct]; }
                }
            }
    }

    // reduce across the 16 lanes (same rows, different cols); tie-break lower index
    #pragma unroll
    for (int r16 = 0; r16 < 16; ++r16) {
        float d  = minv[r16];
        int   ix = mini[r16];
        #pragma unroll
        for (int off = 1; off < 16; off <<= 1) {
            float od = __shfl_xor(d, off);
            int   oi = __shfl_xor(ix, off);
            if (od < d || (od == d && oi < ix)) { d = od; ix = oi; }
        }
        if (l15 == 0) {
            int row_local = wr*64 + (r16 >> 2)*16 + quad*4 + (r16 & 3);
            red_d[row_local][wc] = d;
            red_i[row_local][wc] = ix;
        }
    }
    __syncthreads();
    // combine the two col-halves, write per-split partials
    if (tid < BM) {
        float d0 = red_d[tid][0], d1 = red_d[tid][1];
        int   i0 = red_i[tid][0], i1 = red_i[tid][1];
        float d; int ix;
        if (d1 < d0 || (d1 == d0 && i1 < i0)) { d = d1; ix = i1; } else { d = d0; ix = i0; }
        pminv[(size_t)(gm + tid) * NSPLIT + split] = d;
        pmini[(size_t)(gm + tid) * NSPLIT + split] = ix;
    }
}

// ---------------- epilogue: reduce NSPLIT partials in-wave, then z_q/z/x/indices ----------------
__global__ void vq_gather(const float* __restrict__ x, const float* __restrict__ cb,
                          const float* __restrict__ pminv, const int* __restrict__ pmini,
                          float* __restrict__ out) {
    int t = blockIdx.x * blockDim.x + threadIdx.x;   // float4 units
    int m = t >> 6;
    int q = t & 63;        // == lane: one wave handles exactly one row

    // 8-way split reduce, replicated across lanes via width-8 xor shuffles
    float d  = pminv[(size_t)m * NSPLIT + (q & 7)];
    int   ix = pmini[(size_t)m * NSPLIT + (q & 7)];
    #pragma unroll
    for (int off = 1; off < NSPLIT; off <<= 1) {
        float od = __shfl_xor(d, off);
        int   oi = __shfl_xor(ix, off);
        if (od < d || (od == d && oi < ix)) { d = od; ix = oi; }
    }

    float4 xv = ((const float4*)x)[t];
    float4 zv = ((const float4*)cb)[(size_t)ix * 64 + q];
    float4 zq;
    zq.x = xv.x + (zv.x - xv.x);
    zq.y = xv.y + (zv.y - xv.y);
    zq.z = xv.z + (zv.z - xv.z);
    zq.w = xv.w + (zv.w - xv.w);
    float4* o = (float4*)out;
    const int ELEM4 = M_TOK * 64;
    o[t]           = zq;     // z_q
    o[t + ELEM4]   = zv;     // z
    o[t + 2*ELEM4] = xv;     // x
    if (q == 0) out[(size_t)3 * M_TOK * K_DIM + m] = (float)ix;
}

// ---------------- launcher ----------------
extern "C" void kernel_launch(void* const* d_in, const int* in_sizes, int n_in,
                              void* d_out, int out_size, void* d_ws, size_t ws_size,
                              hipStream_t stream) {
    const float* x  = (const float*)d_in[0];   // 16384 x 256
    const float* cb = (const float*)d_in[1];   // 8192 x 256
    float* out = (float*)d_out;

    // workspace layout
    char* p = (char*)d_ws;
    unsigned short* xh = (unsigned short*)p;  p += (size_t)M_TOK  * K_DIM * 2;  // 8 MB
    unsigned short* xl = (unsigned short*)p;  p += (size_t)M_TOK  * K_DIM * 2;  // 8 MB
    unsigned short* wh = (unsigned short*)p;  p += (size_t)N_CODE * K_DIM * 2;  // 4 MB
    unsigned short* wl = (unsigned short*)p;  p += (size_t)N_CODE * K_DIM * 2;  // 4 MB
    float* x2    = (float*)p;  p += (size_t)M_TOK * 4;
    float* w2    = (float*)p;  p += (size_t)N_CODE * 4;
    float* pminv = (float*)p;  p += (size_t)M_TOK * NSPLIT * 4;   // 512 KB
    int*   pmini = (int*)p;    p += (size_t)M_TOK * NSPLIT * 4;   // 512 KB

    // prep: one wave per row, 24576 rows
    {
        int waves = M_TOK + N_CODE;
        vq_prep<<<(waves * 64 + 255) / 256, 256, 0, stream>>>(x, cb, xh, xl, wh, wl, x2, w2);
    }
    // main fused MFMA GEMM + argmin
    {
        dim3 grid(NSPLIT, M_TOK / BM);   // 8 x 128 = 1024 blocks -> 4 blocks/CU
        vq_main_mfma<<<grid, 256, 0, stream>>>(xh, xl, wh, wl, x2, w2, pminv, pmini);
    }
    // epilogue (split-reduce fused in)
    {
        int t = M_TOK * (K_DIM / 4);     // 1048576 float4 threads
        vq_gather<<<t / 256, 256, 0, stream>>>(x, cb, pminv, pmini, out);
    }
}

// Round 4
// 307.586 us; speedup vs baseline: 1.6394x; 1.6394x over previous
//
#include <hip/hip_runtime.h>
#include <hip/hip_bf16.h>
#include <cstddef>
#include <cstdint>

// ---------------- problem constants ----------------
#define M_TOK   16384      // 32*512 tokens
#define N_CODE  8192       // NUM_LATENTS
#define K_DIM   256        // LATENT_DIM
#define NSPLIT  8          // 1024 blocks = 4 blocks/CU (LDS 34.8KB*4 < 160KB; VGPR 104*4 waves <= 512)
#define BM      128
#define BN      128
#define BK      32

typedef short bf16x8 __attribute__((ext_vector_type(8)));  // 8 bf16 = 4 VGPRs
typedef float f32x4  __attribute__((ext_vector_type(4)));

__device__ __forceinline__ unsigned short f2bf_rne(float f) {
    unsigned u = __float_as_uint(f);
    unsigned r = u + 0x7FFFu + ((u >> 16) & 1u);
    return (unsigned short)(r >> 16);
}
__device__ __forceinline__ float bf2f(unsigned short h) {
    union { unsigned u; float f; } c; c.u = ((unsigned)h) << 16; return c.f;
}

__device__ __forceinline__ void gload16(const void* g, void* l) {
    __builtin_amdgcn_global_load_lds(
        (const __attribute__((address_space(1))) void*)g,
        (__attribute__((address_space(3))) void*)l, 16, 0, 0);
}

// ---------------- prep: bf16 hi/lo split + fp32 norms ----------------
// one wave per row; lane l handles float4 l (256 floats = 64 lanes * 4)
__global__ void vq_prep(const float* __restrict__ x, const float* __restrict__ cb,
                        unsigned short* __restrict__ xh, unsigned short* __restrict__ xl,
                        unsigned short* __restrict__ wh, unsigned short* __restrict__ wl,
                        float* __restrict__ x2, float* __restrict__ w2) {
    int gt   = blockIdx.x * blockDim.x + threadIdx.x;
    int row  = gt >> 6;
    int lane = gt & 63;
    if (row >= M_TOK + N_CODE) return;
    const float* src; unsigned short *dh, *dl; float* dn;
    if (row < M_TOK) {
        src = x + (size_t)row * K_DIM;
        dh = xh + (size_t)row * K_DIM; dl = xl + (size_t)row * K_DIM; dn = x2 + row;
    } else {
        int r = row - M_TOK;
        src = cb + (size_t)r * K_DIM;
        dh = wh + (size_t)r * K_DIM; dl = wl + (size_t)r * K_DIM; dn = w2 + r;
    }
    float4 v = ((const float4*)src)[lane];
    unsigned short h0 = f2bf_rne(v.x), h1 = f2bf_rne(v.y);
    unsigned short h2 = f2bf_rne(v.z), h3 = f2bf_rne(v.w);
    unsigned short l0 = f2bf_rne(v.x - bf2f(h0)), l1 = f2bf_rne(v.y - bf2f(h1));
    unsigned short l2 = f2bf_rne(v.z - bf2f(h2)), l3 = f2bf_rne(v.w - bf2f(h3));
    ushort4 hv; hv.x = h0; hv.y = h1; hv.z = h2; hv.w = h3;
    ushort4 lv; lv.x = l0; lv.y = l1; lv.z = l2; lv.w = l3;
    ((ushort4*)dh)[lane] = hv;
    ((ushort4*)dl)[lane] = lv;
    float s = v.x*v.x + v.y*v.y + v.z*v.z + v.w*v.w;
    #pragma unroll
    for (int off = 32; off > 0; off >>= 1) s += __shfl_down(s, off);
    if (lane == 0) *dn = s;
}

// ---------------- main: 3-term bf16 MFMA GEMM fused with argmin ----------------
// R4: NSPLIT=8 kept (occupancy 45% confirmed in R3), launch_bounds back to (256,2):
// (256,4) forced VGPR 104->64 -> acc[4][4] spilled to scratch (WRITE_SIZE 2MB->279MB,
// FETCH +830MB, MfmaUtil 40->21). (256,2) keeps 104 VGPR which already permits 4 waves/EU.
__global__ __launch_bounds__(256, 2)
void vq_main_mfma(const unsigned short* __restrict__ xh, const unsigned short* __restrict__ xl,
                  const unsigned short* __restrict__ wh, const unsigned short* __restrict__ wl,
                  const float* __restrict__ x2, const float* __restrict__ w2,
                  float* __restrict__ pminv, int* __restrict__ pmini) {
    // LDS tiles: [128 rows][32 bf16] row-major, 64 B per row (8 KB each)
    __shared__ unsigned short xh_s[BM][BK];
    __shared__ unsigned short xl_s[BM][BK];
    __shared__ unsigned short wh_s[BN][BK];
    __shared__ unsigned short wl_s[BN][BK];
    __shared__ float red_d[BM][2];
    __shared__ int   red_i[BM][2];

    const int split = blockIdx.x;            // 0..NSPLIT-1
    const int mtile = blockIdx.y;            // 0..127
    const int gm    = mtile * BM;
    const int tid   = threadIdx.x;
    const int w     = tid >> 6;              // wave 0..3
    const int lane  = tid & 63;
    const int wr    = w >> 1;                // row half (0/1)
    const int wc    = w & 1;                 // col half (0/1)
    const int quad  = lane >> 4;             // 0..3
    const int l15   = lane & 15;

    // staging addressing (wave w stages rows [w*32, w*32+32) of each array)
    const int w32   = w * 32;
    const int srow  = (lane >> 2);           // 0..15 within 16-row chunk
    const int sc16  = (lane & 3) * 16;       // byte offset within 64B row chunk

    // per-lane row constants
    float x2r[16];
    #pragma unroll
    for (int rt = 0; rt < 4; ++rt)
        #pragma unroll
        for (int reg = 0; reg < 4; ++reg)
            x2r[rt*4+reg] = x2[gm + wr*64 + rt*16 + quad*4 + reg];

    float minv[16];
    int   mini[16];
    #pragma unroll
    for (int i = 0; i < 16; ++i) { minv[i] = 3.4e38f; mini[i] = 0; }

    const char* xhp = (const char*)xh;
    const char* xlp = (const char*)xl;
    const char* whp = (const char*)wh;
    const char* wlp = (const char*)wl;

    const int tiles = (N_CODE / NSPLIT) / BN;    // 8
    for (int tile = 0; tile < tiles; ++tile) {
        const int nb = split * (N_CODE / NSPLIT) + tile * BN;

        f32x4 acc[4][4];
        #pragma unroll
        for (int rt = 0; rt < 4; ++rt)
            #pragma unroll
            for (int ct = 0; ct < 4; ++ct)
                acc[rt][ct] = (f32x4){0.f, 0.f, 0.f, 0.f};

        for (int kc = 0; kc < K_DIM / BK; ++kc) {
            __syncthreads();     // protect LDS from previous iteration's readers
            #pragma unroll
            for (int i = 0; i < 2; ++i) {
                int r = w32 + i * 16 + srow;            // tile row this lane fetches
                size_t xoff = (size_t)(gm + r) * (K_DIM*2) + kc*(BK*2) + sc16;
                size_t woff = (size_t)(nb + r) * (K_DIM*2) + kc*(BK*2) + sc16;
                unsigned ldso = (unsigned)(w32 + i * 16) * (BK*2);
                gload16(xhp + xoff, (char*)&xh_s[0][0] + ldso);
                gload16(xlp + xoff, (char*)&xl_s[0][0] + ldso);
                gload16(whp + woff, (char*)&wh_s[0][0] + ldso);
                gload16(wlp + woff, (char*)&wl_s[0][0] + ldso);
            }
            __syncthreads();     // staging complete

            bf16x8 ah[4], al[4], bh[4], bl[4];
            const int ko = quad * 16;    // byte offset along K: (lane>>4)*8 bf16
            #pragma unroll
            for (int rt = 0; rt < 4; ++rt) {
                int off = (wr*64 + rt*16 + l15) * (BK*2) + ko;
                ah[rt] = *(const bf16x8*)((const char*)&xh_s[0][0] + off);
                al[rt] = *(const bf16x8*)((const char*)&xl_s[0][0] + off);
            }
            #pragma unroll
            for (int ct = 0; ct < 4; ++ct) {
                int off = (wc*64 + ct*16 + l15) * (BK*2) + ko;
                bh[ct] = *(const bf16x8*)((const char*)&wh_s[0][0] + off);
                bl[ct] = *(const bf16x8*)((const char*)&wl_s[0][0] + off);
            }
            #pragma unroll
            for (int rt = 0; rt < 4; ++rt)
                #pragma unroll
                for (int ct = 0; ct < 4; ++ct) {
                    acc[rt][ct] = __builtin_amdgcn_mfma_f32_16x16x32_bf16(al[rt], bh[ct], acc[rt][ct], 0, 0, 0);
                    acc[rt][ct] = __builtin_amdgcn_mfma_f32_16x16x32_bf16(ah[rt], bl[ct], acc[rt][ct], 0, 0, 0);
                    acc[rt][ct] = __builtin_amdgcn_mfma_f32_16x16x32_bf16(ah[rt], bh[ct], acc[rt][ct], 0, 0, 0);
                }
        }

        // score tile: dist = (x2 - 2*xw) + w2, C layout col=lane&15, row=quad*4+reg
        float w2c[4];
        int   cidx[4];
        #pragma unroll
        for (int ct = 0; ct < 4; ++ct) {
            cidx[ct] = nb + wc*64 + ct*16 + l15;
            w2c[ct]  = w2[cidx[ct]];
        }
        #pragma unroll
        for (int rt = 0; rt < 4; ++rt)
            #pragma unroll
            for (int ct = 0; ct < 4; ++ct) {
                #pragma unroll
                for (int reg = 0; reg < 4; ++reg) {
                    float d = (x2r[rt*4+reg] - 2.0f * acc[rt][ct][reg]) + w2c[ct];
                    int r16 = rt*4 + reg;
                    if (d < minv[r16]) { minv[r16] = d; mini[r16] = cidx[ct]; }
                }
            }
    }

    // reduce across the 16 lanes (same rows, different cols); tie-break lower index
    #pragma unroll
    for (int r16 = 0; r16 < 16; ++r16) {
        float d  = minv[r16];
        int   ix = mini[r16];
        #pragma unroll
        for (int off = 1; off < 16; off <<= 1) {
            float od = __shfl_xor(d, off);
            int   oi = __shfl_xor(ix, off);
            if (od < d || (od == d && oi < ix)) { d = od; ix = oi; }
        }
        if (l15 == 0) {
            int row_local = wr*64 + (r16 >> 2)*16 + quad*4 + (r16 & 3);
            red_d[row_local][wc] = d;
            red_i[row_local][wc] = ix;
        }
    }
    __syncthreads();
    // combine the two col-halves, write per-split partials
    if (tid < BM) {
        float d0 = red_d[tid][0], d1 = red_d[tid][1];
        int   i0 = red_i[tid][0], i1 = red_i[tid][1];
        float d; int ix;
        if (d1 < d0 || (d1 == d0 && i1 < i0)) { d = d1; ix = i1; } else { d = d0; ix = i0; }
        pminv[(size_t)(gm + tid) * NSPLIT + split] = d;
        pmini[(size_t)(gm + tid) * NSPLIT + split] = ix;
    }
}

// ---------------- epilogue: reduce NSPLIT partials in-wave, then z_q/z/x/indices ----------------
__global__ void vq_gather(const float* __restrict__ x, const float* __restrict__ cb,
                          const float* __restrict__ pminv, const int* __restrict__ pmini,
                          float* __restrict__ out) {
    int t = blockIdx.x * blockDim.x + threadIdx.x;   // float4 units
    int m = t >> 6;
    int q = t & 63;        // == lane: one wave handles exactly one row

    // 8-way split reduce, replicated across lanes via width-8 xor shuffles
    float d  = pminv[(size_t)m * NSPLIT + (q & 7)];
    int   ix = pmini[(size_t)m * NSPLIT + (q & 7)];
    #pragma unroll
    for (int off = 1; off < NSPLIT; off <<= 1) {
        float od = __shfl_xor(d, off);
        int   oi = __shfl_xor(ix, off);
        if (od < d || (od == d && oi < ix)) { d = od; ix = oi; }
    }

    float4 xv = ((const float4*)x)[t];
    float4 zv = ((const float4*)cb)[(size_t)ix * 64 + q];
    float4 zq;
    zq.x = xv.x + (zv.x - xv.x);
    zq.y = xv.y + (zv.y - xv.y);
    zq.z = xv.z + (zv.z - xv.z);
    zq.w = xv.w + (zv.w - xv.w);
    float4* o = (float4*)out;
    const int ELEM4 = M_TOK * 64;
    o[t]           = zq;     // z_q
    o[t + ELEM4]   = zv;     // z
    o[t + 2*ELEM4] = xv;     // x
    if (q == 0) out[(size_t)3 * M_TOK * K_DIM + m] = (float)ix;
}

// ---------------- launcher ----------------
extern "C" void kernel_launch(void* const* d_in, const int* in_sizes, int n_in,
                              void* d_out, int out_size, void* d_ws, size_t ws_size,
                              hipStream_t stream) {
    const float* x  = (const float*)d_in[0];   // 16384 x 256
    const float* cb = (const float*)d_in[1];   // 8192 x 256
    float* out = (float*)d_out;

    // workspace layout
    char* p = (char*)d_ws;
    unsigned short* xh = (unsigned short*)p;  p += (size_t)M_TOK  * K_DIM * 2;  // 8 MB
    unsigned short* xl = (unsigned short*)p;  p += (size_t)M_TOK  * K_DIM * 2;  // 8 MB
    unsigned short* wh = (unsigned short*)p;  p += (size_t)N_CODE * K_DIM * 2;  // 4 MB
    unsigned short* wl = (unsigned short*)p;  p += (size_t)N_CODE * K_DIM * 2;  // 4 MB
    float* x2    = (float*)p;  p += (size_t)M_TOK * 4;
    float* w2    = (float*)p;  p += (size_t)N_CODE * 4;
    float* pminv = (float*)p;  p += (size_t)M_TOK * NSPLIT * 4;   // 512 KB
    int*   pmini = (int*)p;    p += (size_t)M_TOK * NSPLIT * 4;   // 512 KB

    // prep: one wave per row, 24576 rows
    {
        int waves = M_TOK + N_CODE;
        vq_prep<<<(waves * 64 + 255) / 256, 256, 0, stream>>>(x, cb, xh, xl, wh, wl, x2, w2);
    }
    // main fused MFMA GEMM + argmin
    {
        dim3 grid(NSPLIT, M_TOK / BM);   // 8 x 128 = 1024 blocks -> 4 blocks/CU
        vq_main_mfma<<<grid, 256, 0, stream>>>(xh, xl, wh, wl, x2, w2, pminv, pmini);
    }
    // epilogue (split-reduce fused in)
    {
        int t = M_TOK * (K_DIM / 4);     // 1048576 float4 threads
        vq_gather<<<t / 256, 256, 0, stream>>>(x, cb, pminv, pmini, out);
    }
}

// Round 5
// 280.236 us; speedup vs baseline: 1.7994x; 1.0976x over previous
//
#include <hip/hip_runtime.h>
#include <hip/hip_bf16.h>
#include <cstddef>
#include <cstdint>

// ---------------- problem constants ----------------
#define M_TOK   16384      // 32*512 tokens
#define N_CODE  8192       // NUM_LATENTS
#define K_DIM   256        // LATENT_DIM
#define NSPLIT  4          // reg-capped at 2 blocks/CU regardless (VGPR+AGPR=168 -> 256 bucket);
                           // 512 blocks amortize prologue better than 1024 (R2 230us vs R4 240us)
#define BM      128
#define BN      128
#define BK      64         // 128B LDS rows = 32 banks; 8x16B chunks XOR-swizzled -> conflict-free

typedef short bf16x8 __attribute__((ext_vector_type(8)));  // 8 bf16 = 4 VGPRs
typedef float f32x4  __attribute__((ext_vector_type(4)));

__device__ __forceinline__ unsigned short f2bf_rne(float f) {
    unsigned u = __float_as_uint(f);
    unsigned r = u + 0x7FFFu + ((u >> 16) & 1u);
    return (unsigned short)(r >> 16);
}
__device__ __forceinline__ float bf2f(unsigned short h) {
    union { unsigned u; float f; } c; c.u = ((unsigned)h) << 16; return c.f;
}

__device__ __forceinline__ void gload16(const void* g, void* l) {
    __builtin_amdgcn_global_load_lds(
        (const __attribute__((address_space(1))) void*)g,
        (__attribute__((address_space(3))) void*)l, 16, 0, 0);
}

// ---------------- prep: bf16 hi/lo split + fp32 norms ----------------
__global__ void vq_prep(const float* __restrict__ x, const float* __restrict__ cb,
                        unsigned short* __restrict__ xh, unsigned short* __restrict__ xl,
                        unsigned short* __restrict__ wh, unsigned short* __restrict__ wl,
                        float* __restrict__ x2, float* __restrict__ w2) {
    int gt   = blockIdx.x * blockDim.x + threadIdx.x;
    int row  = gt >> 6;
    int lane = gt & 63;
    if (row >= M_TOK + N_CODE) return;
    const float* src; unsigned short *dh, *dl; float* dn;
    if (row < M_TOK) {
        src = x + (size_t)row * K_DIM;
        dh = xh + (size_t)row * K_DIM; dl = xl + (size_t)row * K_DIM; dn = x2 + row;
    } else {
        int r = row - M_TOK;
        src = cb + (size_t)r * K_DIM;
        dh = wh + (size_t)r * K_DIM; dl = wl + (size_t)r * K_DIM; dn = w2 + r;
    }
    float4 v = ((const float4*)src)[lane];
    unsigned short h0 = f2bf_rne(v.x), h1 = f2bf_rne(v.y);
    unsigned short h2 = f2bf_rne(v.z), h3 = f2bf_rne(v.w);
    unsigned short l0 = f2bf_rne(v.x - bf2f(h0)), l1 = f2bf_rne(v.y - bf2f(h1));
    unsigned short l2 = f2bf_rne(v.z - bf2f(h2)), l3 = f2bf_rne(v.w - bf2f(h3));
    ushort4 hv; hv.x = h0; hv.y = h1; hv.z = h2; hv.w = h3;
    ushort4 lv; lv.x = l0; lv.y = l1; lv.z = l2; lv.w = l3;
    ((ushort4*)dh)[lane] = hv;
    ((ushort4*)dl)[lane] = lv;
    float s = v.x*v.x + v.y*v.y + v.z*v.z + v.w*v.w;
    #pragma unroll
    for (int off = 32; off > 0; off >>= 1) s += __shfl_down(s, off);
    if (lane == 0) *dn = s;
}

// ---------------- main: 3-term bf16 MFMA GEMM fused with argmin ----------------
// R5: BK=64 + XOR-swizzled 16B chunks. LDS chunk for (row, K-chunk g) lives at slot
// s = g ^ (row & 7). Staging permutes WHICH global chunk each lane fetches (LDS side of
// global_load_lds is fixed uniform-base + lane*16). Fragment reads then hit all 8 bank
// groups with 2-way aliasing (free) instead of the old 8-way conflict (+4 cyc/read,
// SQ_LDS_BANK_CONFLICT=16.8M). Accumulation order identical to R2 -> bit-exact scores.
__global__ __launch_bounds__(256, 2)
void vq_main_mfma(const unsigned short* __restrict__ xh, const unsigned short* __restrict__ xl,
                  const unsigned short* __restrict__ wh, const unsigned short* __restrict__ wl,
                  const float* __restrict__ x2, const float* __restrict__ w2,
                  float* __restrict__ pminv, int* __restrict__ pmini) {
    // [128 rows][64 bf16] = 128 B row = exactly 32 banks; 16 KB each
    __shared__ unsigned short xh_s[BM][BK];
    __shared__ unsigned short xl_s[BM][BK];
    __shared__ unsigned short wh_s[BN][BK];
    __shared__ unsigned short wl_s[BN][BK];
    __shared__ float red_d[BM][2];
    __shared__ int   red_i[BM][2];

    const int split = blockIdx.x;            // 0..NSPLIT-1
    const int mtile = blockIdx.y;            // 0..127
    const int gm    = mtile * BM;
    const int tid   = threadIdx.x;
    const int w     = tid >> 6;              // wave 0..3
    const int lane  = tid & 63;
    const int wr    = w >> 1;                // row half (0/1)
    const int wc    = w & 1;                 // col half (0/1)
    const int quad  = lane >> 4;             // 0..3
    const int l15   = lane & 15;

    // staging addressing: wave w stages rows [w*32, w*32+32) of each array.
    // round i (0..3): lane covers row w*32 + i*8 + (lane>>3), swizzled global chunk
    // g = (lane&7) ^ (lane>>3)  (row&7 == lane>>3 since i*8 and w*32 are mult of 8)
    const int w32   = w * 32;
    const int srl   = lane >> 3;                       // 0..7
    const int sg    = (lane & 7) ^ srl;                // global 16B chunk this lane fetches

    // per-lane row constants
    float x2r[16];
    #pragma unroll
    for (int rt = 0; rt < 4; ++rt)
        #pragma unroll
        for (int reg = 0; reg < 4; ++reg)
            x2r[rt*4+reg] = x2[gm + wr*64 + rt*16 + quad*4 + reg];

    float minv[16];
    int   mini[16];
    #pragma unroll
    for (int i = 0; i < 16; ++i) { minv[i] = 3.4e38f; mini[i] = 0; }

    const char* xhp = (const char*)xh;
    const char* xlp = (const char*)xl;
    const char* whp = (const char*)wh;
    const char* wlp = (const char*)wl;

    const int tiles = (N_CODE / NSPLIT) / BN;    // 16
    for (int tile = 0; tile < tiles; ++tile) {
        const int nb = split * (N_CODE / NSPLIT) + tile * BN;

        f32x4 acc[4][4];
        #pragma unroll
        for (int rt = 0; rt < 4; ++rt)
            #pragma unroll
            for (int ct = 0; ct < 4; ++ct)
                acc[rt][ct] = (f32x4){0.f, 0.f, 0.f, 0.f};

        for (int kc = 0; kc < K_DIM / BK; ++kc) {    // 4
            __syncthreads();     // protect LDS from previous iteration's readers
            #pragma unroll
            for (int i = 0; i < 4; ++i) {
                int rowl = w32 + i * 8 + srl;        // tile row this lane fetches
                size_t xoff = (size_t)(gm + rowl) * (K_DIM*2) + kc*(BK*2) + sg*16;
                size_t woff = (size_t)(nb + rowl) * (K_DIM*2) + kc*(BK*2) + sg*16;
                unsigned ldso = (unsigned)w32 * (BK*2) + i * 1024;   // wave-uniform
                gload16(xhp + xoff, (char*)&xh_s[0][0] + ldso);
                gload16(xlp + xoff, (char*)&xl_s[0][0] + ldso);
                gload16(whp + woff, (char*)&wh_s[0][0] + ldso);
                gload16(wlp + woff, (char*)&wl_s[0][0] + ldso);
            }
            __syncthreads();     // staging complete

            #pragma unroll
            for (int ks = 0; ks < 2; ++ks) {         // two 32-K steps within BK=64
                bf16x8 ah[4], al[4], bh[4], bl[4];
                const int sl = ((ks << 2) + quad) ^ (l15 & 7);   // swizzled slot
                #pragma unroll
                for (int rt = 0; rt < 4; ++rt) {
                    int off = (wr*64 + rt*16 + l15) * (BK*2) + sl*16;
                    ah[rt] = *(const bf16x8*)((const char*)&xh_s[0][0] + off);
                    al[rt] = *(const bf16x8*)((const char*)&xl_s[0][0] + off);
                }
                #pragma unroll
                for (int ct = 0; ct < 4; ++ct) {
                    int off = (wc*64 + ct*16 + l15) * (BK*2) + sl*16;
                    bh[ct] = *(const bf16x8*)((const char*)&wh_s[0][0] + off);
                    bl[ct] = *(const bf16x8*)((const char*)&wl_s[0][0] + off);
                }
                #pragma unroll
                for (int rt = 0; rt < 4; ++rt)
                    #pragma unroll
                    for (int ct = 0; ct < 4; ++ct) {
                        acc[rt][ct] = __builtin_amdgcn_mfma_f32_16x16x32_bf16(al[rt], bh[ct], acc[rt][ct], 0, 0, 0);
                        acc[rt][ct] = __builtin_amdgcn_mfma_f32_16x16x32_bf16(ah[rt], bl[ct], acc[rt][ct], 0, 0, 0);
                        acc[rt][ct] = __builtin_amdgcn_mfma_f32_16x16x32_bf16(ah[rt], bh[ct], acc[rt][ct], 0, 0, 0);
                    }
            }
        }

        // score tile: dist = (x2 - 2*xw) + w2, C layout col=lane&15, row=quad*4+reg
        float w2c[4];
        int   cidx[4];
        #pragma unroll
        for (int ct = 0; ct < 4; ++ct) {
            cidx[ct] = nb + wc*64 + ct*16 + l15;
            w2c[ct]  = w2[cidx[ct]];
        }
        #pragma unroll
        for (int rt = 0; rt < 4; ++rt)
            #pragma unroll
            for (int ct = 0; ct < 4; ++ct) {
                #pragma unroll
                for (int reg = 0; reg < 4; ++reg) {
                    float d = (x2r[rt*4+reg] - 2.0f * acc[rt][ct][reg]) + w2c[ct];
                    int r16 = rt*4 + reg;
                    if (d < minv[r16]) { minv[r16] = d; mini[r16] = cidx[ct]; }
                }
            }
    }

    // reduce across the 16 lanes (same rows, different cols); tie-break lower index
    #pragma unroll
    for (int r16 = 0; r16 < 16; ++r16) {
        float d  = minv[r16];
        int   ix = mini[r16];
        #pragma unroll
        for (int off = 1; off < 16; off <<= 1) {
            float od = __shfl_xor(d, off);
            int   oi = __shfl_xor(ix, off);
            if (od < d || (od == d && oi < ix)) { d = od; ix = oi; }
        }
        if (l15 == 0) {
            int row_local = wr*64 + (r16 >> 2)*16 + quad*4 + (r16 & 3);
            red_d[row_local][wc] = d;
            red_i[row_local][wc] = ix;
        }
    }
    __syncthreads();
    // combine the two col-halves, write per-split partials
    if (tid < BM) {
        float d0 = red_d[tid][0], d1 = red_d[tid][1];
        int   i0 = red_i[tid][0], i1 = red_i[tid][1];
        float d; int ix;
        if (d1 < d0 || (d1 == d0 && i1 < i0)) { d = d1; ix = i1; } else { d = d0; ix = i0; }
        pminv[(size_t)(gm + tid) * NSPLIT + split] = d;
        pmini[(size_t)(gm + tid) * NSPLIT + split] = ix;
    }
}

// ---------------- epilogue: reduce NSPLIT partials in-wave, then z_q/z/x/indices ----------------
__global__ void vq_gather(const float* __restrict__ x, const float* __restrict__ cb,
                          const float* __restrict__ pminv, const int* __restrict__ pmini,
                          float* __restrict__ out) {
    int t = blockIdx.x * blockDim.x + threadIdx.x;   // float4 units
    int m = t >> 6;
    int q = t & 63;        // == lane: one wave handles exactly one row

    // NSPLIT-way split reduce, replicated across lanes via xor shuffles
    float d  = pminv[(size_t)m * NSPLIT + (q & (NSPLIT-1))];
    int   ix = pmini[(size_t)m * NSPLIT + (q & (NSPLIT-1))];
    #pragma unroll
    for (int off = 1; off < NSPLIT; off <<= 1) {
        float od = __shfl_xor(d, off);
        int   oi = __shfl_xor(ix, off);
        if (od < d || (od == d && oi < ix)) { d = od; ix = oi; }
    }

    float4 xv = ((const float4*)x)[t];
    float4 zv = ((const float4*)cb)[(size_t)ix * 64 + q];
    float4 zq;
    zq.x = xv.x + (zv.x - xv.x);
    zq.y = xv.y + (zv.y - xv.y);
    zq.z = xv.z + (zv.z - xv.z);
    zq.w = xv.w + (zv.w - xv.w);
    float4* o = (float4*)out;
    const int ELEM4 = M_TOK * 64;
    o[t]           = zq;     // z_q
    o[t + ELEM4]   = zv;     // z
    o[t + 2*ELEM4] = xv;     // x
    if (q == 0) out[(size_t)3 * M_TOK * K_DIM + m] = (float)ix;
}

// ---------------- launcher ----------------
extern "C" void kernel_launch(void* const* d_in, const int* in_sizes, int n_in,
                              void* d_out, int out_size, void* d_ws, size_t ws_size,
                              hipStream_t stream) {
    const float* x  = (const float*)d_in[0];   // 16384 x 256
    const float* cb = (const float*)d_in[1];   // 8192 x 256
    float* out = (float*)d_out;

    // workspace layout
    char* p = (char*)d_ws;
    unsigned short* xh = (unsigned short*)p;  p += (size_t)M_TOK  * K_DIM * 2;  // 8 MB
    unsigned short* xl = (unsigned short*)p;  p += (size_t)M_TOK  * K_DIM * 2;  // 8 MB
    unsigned short* wh = (unsigned short*)p;  p += (size_t)N_CODE * K_DIM * 2;  // 4 MB
    unsigned short* wl = (unsigned short*)p;  p += (size_t)N_CODE * K_DIM * 2;  // 4 MB
    float* x2    = (float*)p;  p += (size_t)M_TOK * 4;
    float* w2    = (float*)p;  p += (size_t)N_CODE * 4;
    float* pminv = (float*)p;  p += (size_t)M_TOK * NSPLIT * 4;
    int*   pmini = (int*)p;    p += (size_t)M_TOK * NSPLIT * 4;

    // prep: one wave per row, 24576 rows
    {
        int waves = M_TOK + N_CODE;
        vq_prep<<<(waves * 64 + 255) / 256, 256, 0, stream>>>(x, cb, xh, xl, wh, wl, x2, w2);
    }
    // main fused MFMA GEMM + argmin
    {
        dim3 grid(NSPLIT, M_TOK / BM);   // 4 x 128 = 512 blocks
        vq_main_mfma<<<grid, 256, 0, stream>>>(xh, xl, wh, wl, x2, w2, pminv, pmini);
    }
    // epilogue (split-reduce fused in)
    {
        int t = M_TOK * (K_DIM / 4);     // 1048576 float4 threads
        vq_gather<<<t / 256, 256, 0, stream>>>(x, cb, pminv, pmini, out);
    }
}